// Round 10
// baseline (92.541 us; speedup 1.0000x reference)
//
#include <hip/hip_runtime.h>
#include <math.h>

#define TWO_PI 6.283185307179586f

// workspace layout (floats)
#define OFF_ET   0ull          // frames [be][f][4096] (inv-FFT output)
#define OFF_E    8388608ull    // spectra E [be][f][2049] float2
#define OFF_MAXP 16781312ull   // 512 partial maxima (4 per be)
#define OFF_Z    16782336ull   // packed Z' [be][f][2048] float2

__device__ __forceinline__ int sw(int i) { return i ^ ((i >> 5) & 31); }

// output position of freq k after DIF radices [8,8,8,4]
__device__ __forceinline__ int posf(int k) {
    return ((k & 7) << 8) | (((k >> 3) & 7) << 5) | (((k >> 6) & 7) << 2) | (k >> 9);
}

__device__ __forceinline__ float2 cmul(float2 a, float2 b) {
    return make_float2(a.x * b.x - a.y * b.y, a.x * b.y + a.y * b.x);
}
__device__ __forceinline__ float2 cadd(float2 a, float2 b) { return make_float2(a.x + b.x, a.y + b.y); }
__device__ __forceinline__ float2 csub(float2 a, float2 b) { return make_float2(a.x - b.x, a.y - b.y); }

#define RH 0.70710678118654752f

// forward radix-8 DIF in place at logical indices i0 + stride*m (swizzled), twiddle theta=2pi*j/(8*stride)
__device__ __forceinline__ void r8f(float2* b, int i0, int stride, float theta) {
    float2 x0 = b[sw(i0)],            x1 = b[sw(i0 + stride)];
    float2 x2 = b[sw(i0 + 2*stride)], x3 = b[sw(i0 + 3*stride)];
    float2 x4 = b[sw(i0 + 4*stride)], x5 = b[sw(i0 + 5*stride)];
    float2 x6 = b[sw(i0 + 6*stride)], x7 = b[sw(i0 + 7*stride)];
    // A = DFT4(x0,x2,x4,x6), B = DFT4(x1,x3,x5,x7), w4 = -i
    float2 t0 = cadd(x0, x4), t1 = csub(x0, x4), t2 = cadd(x2, x6), t3 = csub(x2, x6);
    float2 A0 = cadd(t0, t2), A2 = csub(t0, t2);
    float2 A1 = make_float2(t1.x + t3.y, t1.y - t3.x);   // t1 - i t3
    float2 A3 = make_float2(t1.x - t3.y, t1.y + t3.x);   // t1 + i t3
    float2 u0 = cadd(x1, x5), u1 = csub(x1, x5), u2 = cadd(x3, x7), u3 = csub(x3, x7);
    float2 B0 = cadd(u0, u2), B2 = csub(u0, u2);
    float2 B1 = make_float2(u1.x + u3.y, u1.y - u3.x);
    float2 B3 = make_float2(u1.x - u3.y, u1.y + u3.x);
    // w8^1 B1, w8^2 B2 = -iB2, w8^3 B3
    float2 b1 = make_float2((B1.x + B1.y) * RH, (B1.y - B1.x) * RH);
    float2 b2 = make_float2(B2.y, -B2.x);
    float2 b3 = make_float2((B3.y - B3.x) * RH, -(B3.x + B3.y) * RH);
    float2 y0 = cadd(A0, B0), y4 = csub(A0, B0);
    float2 y1 = cadd(A1, b1), y5 = csub(A1, b1);
    float2 y2 = cadd(A2, b2), y6 = csub(A2, b2);
    float2 y3 = cadd(A3, b3), y7 = csub(A3, b3);
    float s1, c1; __sincosf(theta, &s1, &c1);
    float2 w1 = make_float2(c1, -s1), w = w1;
    y1 = cmul(y1, w); w = cmul(w, w1);
    y2 = cmul(y2, w); w = cmul(w, w1);
    y3 = cmul(y3, w); w = cmul(w, w1);
    y4 = cmul(y4, w); w = cmul(w, w1);
    y5 = cmul(y5, w); w = cmul(w, w1);
    y6 = cmul(y6, w); w = cmul(w, w1);
    y7 = cmul(y7, w);
    b[sw(i0)]            = y0; b[sw(i0 + stride)]   = y1;
    b[sw(i0 + 2*stride)] = y2; b[sw(i0 + 3*stride)] = y3;
    b[sw(i0 + 4*stride)] = y4; b[sw(i0 + 5*stride)] = y5;
    b[sw(i0 + 6*stride)] = y6; b[sw(i0 + 7*stride)] = y7;
}

// forward radix-4 (stride 1, no twiddle) in place
__device__ __forceinline__ void r4f(float2* b, int i0) {
    float2 a0 = b[sw(i0)], a1 = b[sw(i0 + 1)], a2 = b[sw(i0 + 2)], a3 = b[sw(i0 + 3)];
    float2 t0 = cadd(a0, a2), t1 = csub(a0, a2), t2 = cadd(a1, a3), t3 = csub(a1, a3);
    b[sw(i0)]     = cadd(t0, t2);
    b[sw(i0 + 1)] = make_float2(t1.x + t3.y, t1.y - t3.x);
    b[sw(i0 + 2)] = csub(t0, t2);
    b[sw(i0 + 3)] = make_float2(t1.x - t3.y, t1.y + t3.x);
}

// inverse radix-8 DIT in place (conjugate twiddle applied BEFORE inverse butterfly)
__device__ __forceinline__ void r8i(float2* b, int i0, int stride, float theta) {
    float2 z0 = b[sw(i0)],            z1 = b[sw(i0 + stride)];
    float2 z2 = b[sw(i0 + 2*stride)], z3 = b[sw(i0 + 3*stride)];
    float2 z4 = b[sw(i0 + 4*stride)], z5 = b[sw(i0 + 5*stride)];
    float2 z6 = b[sw(i0 + 6*stride)], z7 = b[sw(i0 + 7*stride)];
    float s1, c1; __sincosf(theta, &s1, &c1);
    float2 w1 = make_float2(c1, s1), w = w1;
    z1 = cmul(z1, w); w = cmul(w, w1);
    z2 = cmul(z2, w); w = cmul(w, w1);
    z3 = cmul(z3, w); w = cmul(w, w1);
    z4 = cmul(z4, w); w = cmul(w, w1);
    z5 = cmul(z5, w); w = cmul(w, w1);
    z6 = cmul(z6, w); w = cmul(w, w1);
    z7 = cmul(z7, w);
    // A = iDFT4(z0,z2,z4,z6), B = iDFT4(z1,z3,z5,z7), w4 = +i
    float2 t0 = cadd(z0, z4), t1 = csub(z0, z4), t2 = cadd(z2, z6), t3 = csub(z2, z6);
    float2 A0 = cadd(t0, t2), A2 = csub(t0, t2);
    float2 A1 = make_float2(t1.x - t3.y, t1.y + t3.x);   // t1 + i t3
    float2 A3 = make_float2(t1.x + t3.y, t1.y - t3.x);   // t1 - i t3
    float2 u0 = cadd(z1, z5), u1 = csub(z1, z5), u2 = cadd(z3, z7), u3 = csub(z3, z7);
    float2 B0 = cadd(u0, u2), B2 = csub(u0, u2);
    float2 B1 = make_float2(u1.x - u3.y, u1.y + u3.x);
    float2 B3 = make_float2(u1.x + u3.y, u1.y - u3.x);
    // w8^{+1} B1, +i B2, w8^{+3} B3
    float2 b1 = make_float2((B1.x - B1.y) * RH, (B1.x + B1.y) * RH);
    float2 b2 = make_float2(-B2.y, B2.x);
    float2 b3 = make_float2(-(B3.x + B3.y) * RH, (B3.x - B3.y) * RH);
    b[sw(i0)]            = cadd(A0, B0); b[sw(i0 + 4*stride)] = csub(A0, B0);
    b[sw(i0 + stride)]   = cadd(A1, b1); b[sw(i0 + 5*stride)] = csub(A1, b1);
    b[sw(i0 + 2*stride)] = cadd(A2, b2); b[sw(i0 + 6*stride)] = csub(A2, b2);
    b[sw(i0 + 3*stride)] = cadd(A3, b3); b[sw(i0 + 7*stride)] = csub(A3, b3);
}

// inverse radix-4 (stride 1, no twiddle)
__device__ __forceinline__ void r4i(float2* b, int i0) {
    float2 a0 = b[sw(i0)], a1 = b[sw(i0 + 1)], a2 = b[sw(i0 + 2)], a3 = b[sw(i0 + 3)];
    float2 t0 = cadd(a0, a2), t1 = csub(a0, a2), t2 = cadd(a1, a3), t3 = csub(a1, a3);
    b[sw(i0)]     = cadd(t0, t2);
    b[sw(i0 + 1)] = make_float2(t1.x - t3.y, t1.y + t3.x);
    b[sw(i0 + 2)] = csub(t0, t2);
    b[sw(i0 + 3)] = make_float2(t1.x + t3.y, t1.y - t3.x);
}

// ---- fused: energy + 4x forward FFT (register radix-8) + per-quarter tf max
__global__ __launch_bounds__(1024, 8) void k_fwd(const float* __restrict__ env,
                                                 const float* __restrict__ noise,
                                                 const float* __restrict__ tf,
                                                 float* __restrict__ ws) {
    __shared__ float2 B2[8192];   // 4 FFTs x 2048 complex = 64 KB
    int tid = threadIdx.x;
    int id = blockIdx.x;
    int xcd = id & 7, slot = id >> 3;
    int be = xcd * 16 + (slot >> 2);
    int fg = slot & 3;
    const float4* env4 = (const float4*)env;
    const float4* noi4 = (const float4*)noise;
    size_t base = (size_t)be * 16384 + fg;
#pragma unroll
    for (int it = 0; it < 2; ++it) {
        int c = tid + it * 1024;
        float4 ea = env4[base + (size_t)(2 * c) * 4];
        float4 eb = env4[base + (size_t)(2 * c + 1) * 4];
        float4 za = noi4[base + (size_t)(2 * c) * 4];
        float4 zb = noi4[base + (size_t)(2 * c + 1) * 4];
        int m = sw(c);
        B2[m]        = make_float2(ea.x * (za.x * 2.f - 1.f), eb.x * (zb.x * 2.f - 1.f));
        B2[2048 + m] = make_float2(ea.y * (za.y * 2.f - 1.f), eb.y * (zb.y * 2.f - 1.f));
        B2[4096 + m] = make_float2(ea.z * (za.z * 2.f - 1.f), eb.z * (zb.z * 2.f - 1.f));
        B2[6144 + m] = make_float2(ea.w * (za.w * 2.f - 1.f), eb.w * (zb.w * 2.f - 1.f));
    }
    __syncthreads();
    int buf = tid >> 8, t = tid & 255;
    float2* bb = B2 + buf * 2048;
    r8f(bb, t, 256, (float)t * (TWO_PI / 2048.f));
    __syncthreads();
    r8f(bb, (t >> 5) * 256 + (t & 31), 32, (float)(t & 31) * (TWO_PI / 256.f));
    __syncthreads();
    r8f(bb, (t >> 2) * 32 + (t & 3), 4, (float)(t & 3) * (TWO_PI / 32.f));
    __syncthreads();
    r4f(bb, 8 * t); r4f(bb, 8 * t + 4);
    __syncthreads();
    // rfft unpack -> E
    float2* Eg = (float2*)(ws + OFF_E) + (size_t)(be * 16 + fg * 4 + buf) * 2049;
#pragma unroll
    for (int it = 0; it < 5; ++it) {
        int k = t + it * 256;
        if (k <= 1024) {
            int pk = sw(posf(k));
            int pm = sw(posf((2048 - k) & 2047));
            float s4, c4; __sincosf((float)k * (TWO_PI / 4096.f), &s4, &c4);
            float2 zk = bb[pk], zm = bb[pm];
            float xer = 0.5f * (zk.x + zm.x), xei = 0.5f * (zk.y - zm.y);
            float xo_r = 0.5f * (zk.y + zm.y), xo_i = 0.5f * (zm.x - zk.x);
            float wr = xo_r * c4 + xo_i * s4;
            float wi = xo_i * c4 - xo_r * s4;
            Eg[k] = make_float2(xer + wr, xei + wi);
            Eg[2048 - k] = make_float2(xer - wr, wi - xei);
        }
    }
    __syncthreads();
    // tf max over this block's bin quarter (reuses B2 as float scratch)
    float* Bf = (float*)B2;
    const float4* ab4 = (const float4*)(tf + (size_t)be * 65568);
    int b0 = fg * 513;
    int nb = (fg == 3) ? 510 : 513;
    float mx = 0.f;
    for (int u = tid; u < nb * 4; u += 1024) {
        int g = u >> 2, e = u & 3;
        int bin = b0 + g;
        float4 A = ab4[bin * 8 + e];
        float4 Bv = ab4[bin * 8 + e + 4];
        mx = fmaxf(mx, fmaxf(fmaxf(A.x * A.x + Bv.x * Bv.x, A.y * A.y + Bv.y * Bv.y),
                             fmaxf(A.z * A.z + Bv.z * Bv.z, A.w * A.w + Bv.w * Bv.w)));
    }
    Bf[tid] = mx;
    __syncthreads();
    for (int s = 512; s > 0; s >>= 1) {
        if (tid < s) Bf[tid] = fmaxf(Bf[tid], Bf[tid + s]);
        __syncthreads();
    }
    if (tid == 0) ws[OFF_MAXP + be * 4 + fg] = Bf[0];
}

// ---- per-bin recurrence on pair (k, 2048-k) + fused irfft pre-pack -> Z' natural order
__global__ __launch_bounds__(256) void k_recur(const float* __restrict__ tf,
                                               float* __restrict__ ws) {
    __shared__ float sm2lo[256 * 17], simlo[256 * 17];
    __shared__ float sm2hi[256 * 17], simhi[256 * 17];
    int tid = threadIdx.x;
    int be = blockIdx.y;
    int k0 = blockIdx.x << 8;
    int hi0 = 1793 - k0;
    const float* tfb = tf + (size_t)be * 65568;
    const float4* ab4 = (const float4*)tfb;
    const float4* im4 = (const float4*)(tfb + 32784);

    for (int u = tid; u < 2048; u += 256) {
        int half = u >> 10, v = u & 1023;
        int g = v >> 2, e = v & 3;
        int bin = half ? (hi0 + g) : (k0 + g);
        float4 A = ab4[bin * 8 + e];
        float4 Bv = ab4[bin * 8 + e + 4];
        float4 I = im4[bin * 4 + e];
        int o = g * 17 + e * 4;
        float* sm = half ? sm2hi : sm2lo;
        float* si = half ? simhi : simlo;
        sm[o + 0] = A.x * A.x + Bv.x * Bv.x;
        sm[o + 1] = A.y * A.y + Bv.y * Bv.y;
        sm[o + 2] = A.z * A.z + Bv.z * Bv.z;
        sm[o + 3] = A.w * A.w + Bv.w * Bv.w;
        si[o + 0] = I.x; si[o + 1] = I.y; si[o + 2] = I.z; si[o + 3] = I.w;
    }
    __syncthreads();

    int k = k0 + tid;
    int m = 2048 - k;
    int rhi = 255 - tid;
    const float* mp = ws + OFF_MAXP + be * 4;
    float m2x = fmaxf(fmaxf(mp[0], mp[1]), fmaxf(mp[2], mp[3]));
    float rden = 1.0f / (sqrtf(m2x) + 1e-8f);
    const float2* Eb = (const float2*)(ws + OFF_E) + (size_t)be * 16 * 2049;
    float2* Zb = (float2*)(ws + OFF_Z) + (size_t)be * 16 * 2048;
    float2 evlo[16], evhi[16];
#pragma unroll
    for (int f = 0; f < 16; ++f) {
        evlo[f] = Eb[(size_t)f * 2049 + k];
        evhi[f] = Eb[(size_t)f * 2049 + m];
    }
    float ym = (k == 0) ? 0.0f : 1.0f;
    float s4, c4; __sincosf((float)k * (TWO_PI / 4096.0f), &s4, &c4);
    const float SCL = 1.0f / 2048.0f;
    float srl = 0.f, sil = 0.f, srh = 0.f, sih = 0.f;
#pragma unroll
    for (int f = 0; f < 16; ++f) {
        float mh = sqrtf(sm2lo[tid * 17 + f]) * rden;
        float ph = atan2f(simlo[tid * 17 + f], mh) * 3.14159265358979f;
        float sp, cp; __sincosf(ph, &sp, &cp);
        float Tr = mh * cp, Ti = mh * sp;
        sil *= ym;
        srl += evlo[f].x; sil += evlo[f].y;
        float nr = srl * Tr - sil * Ti;
        sil = srl * Ti + sil * Tr; srl = nr;
        float mh2 = sqrtf(sm2hi[rhi * 17 + f]) * rden;
        float ph2 = atan2f(simhi[rhi * 17 + f], mh2) * 3.14159265358979f;
        float sp2, cp2; __sincosf(ph2, &sp2, &cp2);
        float Tr2 = mh2 * cp2, Ti2 = mh2 * sp2;
        sih *= ym;
        srh += evhi[f].x; sih += evhi[f].y;
        float nr2 = srh * Tr2 - sih * Ti2;
        sih = srh * Ti2 + sih * Tr2; srh = nr2;
        float2* Zf = Zb + (size_t)f * 2048;
        if (k == 0) {
            float y0 = srl * SCL, yn = srh * SCL;
            Zf[0] = make_float2(0.5f * (y0 + yn), 0.5f * (y0 - yn));
        } else {
            float ykr = srl * SCL, yki = sil * SCL;
            float ymr = srh * SCL, ymi = sih * SCL;
            float er = 0.5f * (ykr + ymr), ei = 0.5f * (yki - ymi);
            float dr = ykr - ymr, di = yki + ymi;
            float orr = 0.5f * (dr * c4 - di * s4);
            float oi = 0.5f * (dr * s4 + di * c4);
            Zf[k] = make_float2(er - oi, ei + orr);
            Zf[m] = make_float2(er + oi, orr - ei);
        }
    }
    if (k0 == 0 && tid == 0) {   // bin 1024 (self-paired)
        float sr = 0.f, si = 0.f;
#pragma unroll
        for (int f = 0; f < 16; ++f) {
            float a = tfb[1024 * 32 + f];
            float b = tfb[1024 * 32 + 16 + f];
            float im = tfb[32784 + 1024 * 16 + f];
            float mh = sqrtf(a * a + b * b) * rden;
            float ph = atan2f(im, mh) * 3.14159265358979f;
            float sp, cp; __sincosf(ph, &sp, &cp);
            float Tr = mh * cp, Ti = mh * sp;
            float2 e = Eb[(size_t)f * 2049 + 1024];
            sr += e.x; si += e.y;
            float nr = sr * Tr - si * Ti;
            si = sr * Ti + si * Tr; sr = nr;
            Zb[(size_t)f * 2048 + 1024] = make_float2(sr * SCL, -si * SCL);
        }
    }
}

// ---- inverse FFT: 4 frames per block, register radix-8 (reverse phases)
__global__ __launch_bounds__(1024, 8) void k_fft_inv(float* __restrict__ ws) {
    __shared__ float2 B2[8192];
    int tid = threadIdx.x;
    int be = blockIdx.x >> 2, fg = blockIdx.x & 3;
    int buf = tid >> 8, t = tid & 255;
    float2* bb = B2 + buf * 2048;
    const float4* Z4 = (const float4*)((float2*)(ws + OFF_Z) + (size_t)(be * 16 + fg * 4 + buf) * 2048);
#pragma unroll
    for (int it = 0; it < 4; ++it) {
        int idx = t + it * 256;
        float4 v = Z4[idx];
        int k0 = idx * 2;
        bb[sw(posf(k0))]     = make_float2(v.x, v.y);
        bb[sw(posf(k0 + 1))] = make_float2(v.z, v.w);
    }
    __syncthreads();
    r4i(bb, 8 * t); r4i(bb, 8 * t + 4);
    __syncthreads();
    r8i(bb, (t >> 2) * 32 + (t & 3), 4, (float)(t & 3) * (TWO_PI / 32.f));
    __syncthreads();
    r8i(bb, (t >> 5) * 256 + (t & 31), 32, (float)(t & 31) * (TWO_PI / 256.f));
    __syncthreads();
    r8i(bb, t, 256, (float)t * (TWO_PI / 2048.f));
    __syncthreads();
    float2* Fg = (float2*)(ws + OFF_ET) + (size_t)(be * 16 + fg * 4 + buf) * 2048;
#pragma unroll
    for (int it = 0; it < 8; ++it) {
        int c = t + it * 256;
        Fg[c] = bb[sw(c)];
    }
}

// ---- gather + fused overlap-add (b uniform per block -> scalar indices)
__global__ __launch_bounds__(256) void k_segment(const float* __restrict__ ws,
                                                 const int* __restrict__ indices,
                                                 float* __restrict__ out) {
    __shared__ int ste[16];
    int tid = threadIdx.x;
    int b = blockIdx.y;
    if (tid < 16) ste[tid] = indices[b * 16 + tid] * 256;
    __syncthreads();
    int g = blockIdx.x * 256 + tid;
    int t = g << 2;
    const float* F = ws + OFF_ET;
    float4 acc = make_float4(0.f, 0.f, 0.f, 0.f);
#pragma unroll
    for (int e = 0; e < 16; ++e) {
        int te = ste[e];
        if (t >= te) {
            int d = t - te;
            int j = d >> 11, r = d & 2047;
            size_t base = (size_t)(b * 16 + e) * 65536;
            float4 v = *(const float4*)(F + base + j * 4096 + r);
            acc.x += v.x; acc.y += v.y; acc.z += v.z; acc.w += v.w;
            if (j >= 1) {
                float4 w = *(const float4*)(F + base + (j - 1) * 4096 + 2048 + r);
                acc.x += w.x; acc.y += w.y; acc.z += w.z; acc.w += w.w;
            }
        }
    }
    ((float4*)out)[(size_t)b * 8192 + g] = acc;
}

extern "C" void kernel_launch(void* const* d_in, const int* in_sizes, int n_in,
                              void* d_out, int out_size, void* d_ws, size_t ws_size,
                              hipStream_t stream) {
    const float* env = (const float*)d_in[0];
    const float* tf = (const float*)d_in[1];
    const float* noise = (const float*)d_in[2];
    const int* indices = (const int*)d_in[3];
    float* ws = (float*)d_ws;
    float* out = (float*)d_out;

    k_fwd<<<dim3(512), dim3(1024), 0, stream>>>(env, noise, tf, ws);
    k_recur<<<dim3(4, 128), dim3(256), 0, stream>>>(tf, ws);
    k_fft_inv<<<dim3(512), dim3(1024), 0, stream>>>(ws);
    k_segment<<<dim3(32, 8), dim3(256), 0, stream>>>(ws, indices, out);
}

// Round 11
// 86.921 us; speedup vs baseline: 1.0647x; 1.0647x over previous
//
#include <hip/hip_runtime.h>
#include <math.h>

#define TWO_PI 6.283185307179586f

// workspace layout (floats)
#define OFF_ET   0ull          // frames [be][f][4096] (inv-FFT output)
#define OFF_E    8388608ull    // spectra E [be][f][2049] float2
#define OFF_MAXP 16781312ull   // 1024 partial maxima (8 per be)
#define OFF_Z    16782336ull   // packed Z' [be][f][2048] float2

__device__ __forceinline__ int swz(int n) { return n ^ ((n >> 5) & 31); }

// position of natural index k after DIF with radices [2,4,4,4,4,4]
__device__ __forceinline__ int permf(int k) {
    return ((k & 1) << 10) | (((k >> 1) & 3) << 8) | (((k >> 3) & 3) << 6)
         | (((k >> 5) & 3) << 4) | (((k >> 7) & 3) << 2) | ((k >> 9) & 3);
}

__device__ __forceinline__ void r4f_core(float* cr, float* ci, int p0, int p1, int p2, int p3,
                                         float c1, float s1, float c2, float s2, float c3, float s3) {
    float ar = cr[p0], ai = ci[p0];
    float br = cr[p1], bi = ci[p1];
    float crr = cr[p2], cri = ci[p2];
    float drr = cr[p3], dri = ci[p3];
    float u0r = ar + crr, u0i = ai + cri;
    float u1r = ar - crr, u1i = ai - cri;
    float u2r = br + drr, u2i = bi + dri;
    float u3r = br - drr, u3i = bi - dri;
    cr[p0] = u0r + u2r; ci[p0] = u0i + u2i;
    float z1r = u1r + u3i, z1i = u1i - u3r;            // u1 - i*u3
    cr[p1] = z1r * c1 + z1i * s1; ci[p1] = z1i * c1 - z1r * s1;
    float z2r = u0r - u2r, z2i = u0i - u2i;
    cr[p2] = z2r * c2 + z2i * s2; ci[p2] = z2i * c2 - z2r * s2;
    float z3r = u1r - u3i, z3i = u1i + u3r;            // u1 + i*u3
    cr[p3] = z3r * c3 + z3i * s3; ci[p3] = z3i * c3 - z3r * s3;
}

__device__ __forceinline__ void r4i_core(float* cr, float* ci, int p0, int p1, int p2, int p3,
                                         float c1, float s1, float c2, float s2, float c3, float s3) {
    float z0r = cr[p0], z0i = ci[p0];
    float z1r = cr[p1], z1i = ci[p1];
    float z2r = cr[p2], z2i = ci[p2];
    float z3r = cr[p3], z3i = ci[p3];
    float t1r = z1r * c1 - z1i * s1, t1i = z1i * c1 + z1r * s1;
    float t2r = z2r * c2 - z2i * s2, t2i = z2i * c2 + z2r * s2;
    float t3r = z3r * c3 - z3i * s3, t3i = z3i * c3 + z3r * s3;
    float u0r = z0r + t2r, u0i = z0i + t2i;
    float u1r = z0r - t2r, u1i = z0i - t2i;
    float u2r = t1r + t3r, u2i = t1i + t3i;
    float u3r = t1r - t3r, u3i = t1i - t3i;
    cr[p0] = u0r + u2r; ci[p0] = u0i + u2i;
    cr[p1] = u1r - u3i; ci[p1] = u1i + u3r;            // u1 + i*u3
    cr[p2] = u0r - u2r; ci[p2] = u0i - u2i;
    cr[p3] = u1r + u3i; ci[p3] = u1i - u3r;            // u1 - i*u3
}

// one radix-4 stage over 2 buffers (1024 butterflies) with 512 threads
#define STAGE2X(CORE, JEXPR, H, ANGEXPR)                                       \
    {                                                                          \
        _Pragma("unroll")                                                      \
        for (int half_ = 0; half_ < 2; ++half_) {                              \
            int b_ = tid + half_ * 512;                                        \
            int i_ = b_ & 511;                                                 \
            float* cr_ = B + (b_ >> 9) * 4096;                                 \
            float* ci_ = cr_ + 2048;                                           \
            int j_ = (JEXPR);                                                  \
            int p0 = swz(j_), p1 = swz(j_ + (H)), p2 = swz(j_ + 2 * (H)),      \
                p3 = swz(j_ + 3 * (H));                                        \
            float s1, c1; __sincosf((ANGEXPR), &s1, &c1);                      \
            float c2 = c1 * c1 - s1 * s1, s2 = 2.f * c1 * s1;                  \
            float c3 = c1 * c2 - s1 * s2, s3 = s1 * c2 + c1 * s2;              \
            CORE(cr_, ci_, p0, p1, p2, p3, c1, s1, c2, s2, c3, s3);            \
        }                                                                      \
    }                                                                          \
    __syncthreads();

// ---- fused: energy + 2x forward FFT + per-eighth tf max (1024 blocks, 4/CU)
__global__ __launch_bounds__(512, 8) void k_fwd(const float* __restrict__ env,
                                                const float* __restrict__ noise,
                                                const float* __restrict__ tf,
                                                float* __restrict__ ws) {
    __shared__ float B[8192];   // 2 FFTs x (cr[2048], ci[2048]) = 32 KB
    int tid = threadIdx.x;
    int id = blockIdx.x;
    int xcd = id & 7, slot = id >> 3;        // 8 fg-blocks of a be share an XCD
    int be = xcd * 16 + (slot >> 3);
    int fg = slot & 7;                       // f = fg*2, fg*2+1
    const float2* env2 = (const float2*)env;
    const float2* noi2 = (const float2*)noise;
    size_t base = (size_t)be * 32768 + fg;   // float2 units; sample n at base + n*8

    // sample n (f pair) -> buffer (n&1 ? ci : cr)[swz(n>>1)]
#pragma unroll
    for (int it = 0; it < 8; ++it) {
        int n = tid + it * 512;
        float2 e = env2[base + (size_t)n * 8];
        float2 z = noi2[base + (size_t)n * 8];
        float v0 = e.x * (z.x * 2.0f - 1.0f);
        float v1 = e.y * (z.y * 2.0f - 1.0f);
        int m = (n & 1) * 2048 + swz(n >> 1);
        B[m] = v0; B[4096 + m] = v1;
    }
    __syncthreads();
    // radix-2 DIF, h=1024 (sincos shared across the 2 buffers)
#pragma unroll
    for (int it = 0; it < 2; ++it) {
        int i = tid + it * 512;
        int sj = swz(i), sjb = swz(i + 1024);
        float s, c; __sincosf((float)i * (TWO_PI / 2048.0f), &s, &c);
#pragma unroll
        for (int j2 = 0; j2 < 2; ++j2) {
            float* cr = B + j2 * 4096;
            float* ci = cr + 2048;
            float ar = cr[sj], ai = ci[sj], br = cr[sjb], bi = ci[sjb];
            float dr = ar - br, di = ai - bi;
            cr[sj] = ar + br; ci[sj] = ai + bi;
            cr[sjb] = dr * c + di * s; ci[sjb] = di * c - dr * s;
        }
    }
    __syncthreads();
    STAGE2X(r4f_core, (i_ >> 8) * 1024 + (i_ & 255), 256, (float)(i_ & 255) * (TWO_PI / 1024.0f));
    STAGE2X(r4f_core, (i_ >> 6) * 256 + (i_ & 63), 64, (float)(i_ & 63) * (TWO_PI / 256.0f));
    STAGE2X(r4f_core, (i_ & 31) * 64 + (i_ >> 5), 16, (float)(i_ >> 5) * (TWO_PI / 64.0f));
    STAGE2X(r4f_core, (i_ & 127) * 16 + (i_ >> 7), 4, (float)(i_ >> 7) * (TWO_PI / 16.0f));
    STAGE2X(r4f_core, i_ * 4, 1, 0.0f);
    // rfft unpack -> E (indices/twiddles shared across the 2 buffers)
    float2* Ebase = (float2*)(ws + OFF_E) + (size_t)(be * 16 + fg * 2) * 2049;
#pragma unroll
    for (int it = 0; it < 3; ++it) {
        int k = tid + it * 512;
        if (k <= 1024) {
            int pk = swz(permf(k));
            int pm = swz(permf((2048 - k) & 2047));
            float s4, c4; __sincosf((float)k * (TWO_PI / 4096.0f), &s4, &c4);
#pragma unroll
            for (int j2 = 0; j2 < 2; ++j2) {
                float* cr = B + j2 * 4096;
                float* ci = cr + 2048;
                float zkr = cr[pk], zki = ci[pk], zmr = cr[pm], zmi = ci[pm];
                float xer = 0.5f * (zkr + zmr), xei = 0.5f * (zki - zmi);
                float xor_ = 0.5f * (zki + zmi), xoi = 0.5f * (zmr - zkr);
                float wr = xor_ * c4 + xoi * s4;
                float wi = xoi * c4 - xor_ * s4;
                float2* Eg = Ebase + (size_t)j2 * 2049;
                Eg[k] = make_float2(xer + wr, xei + wi);
                Eg[2048 - k] = make_float2(xer - wr, wi - xei);
            }
        }
    }
    __syncthreads();
    // tf max over this block's bin eighth (reuses B)
    const float4* ab4 = (const float4*)(tf + (size_t)be * 65568);
    int b0 = fg * 257;
    int nb = (fg == 7) ? 250 : 257;          // 7*257 + 250 = 2049 bins
    float mx = 0.f;
    for (int u = tid; u < nb * 4; u += 512) {
        int g = u >> 2, e = u & 3;
        int bin = b0 + g;
        float4 A = ab4[bin * 8 + e];
        float4 Bv = ab4[bin * 8 + e + 4];
        mx = fmaxf(mx, fmaxf(fmaxf(A.x * A.x + Bv.x * Bv.x, A.y * A.y + Bv.y * Bv.y),
                             fmaxf(A.z * A.z + Bv.z * Bv.z, A.w * A.w + Bv.w * Bv.w)));
    }
    B[tid] = mx;
    __syncthreads();
    for (int s = 256; s > 0; s >>= 1) {
        if (tid < s) B[tid] = fmaxf(B[tid], B[tid + s]);
        __syncthreads();
    }
    if (tid == 0) ws[OFF_MAXP + be * 8 + fg] = B[0];
}

// ---- per-bin recurrence on pair (k, 2048-k) + fused irfft pre-pack -> Z' natural order
__global__ __launch_bounds__(256) void k_recur(const float* __restrict__ tf,
                                               float* __restrict__ ws) {
    __shared__ float sm2lo[256 * 17], simlo[256 * 17];
    __shared__ float sm2hi[256 * 17], simhi[256 * 17];
    int tid = threadIdx.x;
    int be = blockIdx.y;
    int k0 = blockIdx.x << 8;          // 0,256,512,768
    int hi0 = 1793 - k0;               // hi bins [hi0, hi0+255]
    const float* tfb = tf + (size_t)be * 65568;
    const float4* ab4 = (const float4*)tfb;
    const float4* im4 = (const float4*)(tfb + 32784);

    for (int u = tid; u < 2048; u += 256) {
        int half = u >> 10, v = u & 1023;
        int g = v >> 2, e = v & 3;
        int bin = half ? (hi0 + g) : (k0 + g);
        float4 A = ab4[bin * 8 + e];
        float4 Bv = ab4[bin * 8 + e + 4];
        float4 I = im4[bin * 4 + e];
        int o = g * 17 + e * 4;
        float* sm = half ? sm2hi : sm2lo;
        float* si = half ? simhi : simlo;
        sm[o + 0] = A.x * A.x + Bv.x * Bv.x;
        sm[o + 1] = A.y * A.y + Bv.y * Bv.y;
        sm[o + 2] = A.z * A.z + Bv.z * Bv.z;
        sm[o + 3] = A.w * A.w + Bv.w * Bv.w;
        si[o + 0] = I.x; si[o + 1] = I.y; si[o + 2] = I.z; si[o + 3] = I.w;
    }
    __syncthreads();

    int k = k0 + tid;
    int m = 2048 - k;
    int rhi = 255 - tid;
    const float* mp = ws + OFF_MAXP + be * 8;
    float m2x = fmaxf(fmaxf(fmaxf(mp[0], mp[1]), fmaxf(mp[2], mp[3])),
                      fmaxf(fmaxf(mp[4], mp[5]), fmaxf(mp[6], mp[7])));
    float rden = 1.0f / (sqrtf(m2x) + 1e-8f);
    const float2* Eb = (const float2*)(ws + OFF_E) + (size_t)be * 16 * 2049;
    float2* Zb = (float2*)(ws + OFF_Z) + (size_t)be * 16 * 2048;
    float2 evlo[16], evhi[16];
#pragma unroll
    for (int f = 0; f < 16; ++f) {
        evlo[f] = Eb[(size_t)f * 2049 + k];
        evhi[f] = Eb[(size_t)f * 2049 + m];
    }
    float ym = (k == 0) ? 0.0f : 1.0f;
    float s4, c4; __sincosf((float)k * (TWO_PI / 4096.0f), &s4, &c4);
    const float SCL = 1.0f / 2048.0f;
    float srl = 0.f, sil = 0.f, srh = 0.f, sih = 0.f;
#pragma unroll
    for (int f = 0; f < 16; ++f) {
        float mh = sqrtf(sm2lo[tid * 17 + f]) * rden;
        float ph = atan2f(simlo[tid * 17 + f], mh) * 3.14159265358979f;
        float sp, cp; __sincosf(ph, &sp, &cp);
        float Tr = mh * cp, Ti = mh * sp;
        sil *= ym;
        srl += evlo[f].x; sil += evlo[f].y;
        float nr = srl * Tr - sil * Ti;
        sil = srl * Ti + sil * Tr; srl = nr;
        float mh2 = sqrtf(sm2hi[rhi * 17 + f]) * rden;
        float ph2 = atan2f(simhi[rhi * 17 + f], mh2) * 3.14159265358979f;
        float sp2, cp2; __sincosf(ph2, &sp2, &cp2);
        float Tr2 = mh2 * cp2, Ti2 = mh2 * sp2;
        sih *= ym;
        srh += evhi[f].x; sih += evhi[f].y;
        float nr2 = srh * Tr2 - sih * Ti2;
        sih = srh * Ti2 + sih * Tr2; srh = nr2;
        float2* Zf = Zb + (size_t)f * 2048;
        if (k == 0) {
            float y0 = srl * SCL, yn = srh * SCL;
            Zf[0] = make_float2(0.5f * (y0 + yn), 0.5f * (y0 - yn));
        } else {
            float ykr = srl * SCL, yki = sil * SCL;
            float ymr = srh * SCL, ymi = sih * SCL;
            float er = 0.5f * (ykr + ymr), ei = 0.5f * (yki - ymi);
            float dr = ykr - ymr, di = yki + ymi;
            float orr = 0.5f * (dr * c4 - di * s4);
            float oi = 0.5f * (dr * s4 + di * c4);
            Zf[k] = make_float2(er - oi, ei + orr);
            Zf[m] = make_float2(er + oi, orr - ei);
        }
    }
    if (k0 == 0 && tid == 0) {   // bin 1024 (self-paired)
        float sr = 0.f, si = 0.f;
#pragma unroll
        for (int f = 0; f < 16; ++f) {
            float a = tfb[1024 * 32 + f];
            float b = tfb[1024 * 32 + 16 + f];
            float im = tfb[32784 + 1024 * 16 + f];
            float mh = sqrtf(a * a + b * b) * rden;
            float ph = atan2f(im, mh) * 3.14159265358979f;
            float sp, cp; __sincosf(ph, &sp, &cp);
            float Tr = mh * cp, Ti = mh * sp;
            float2 e = Eb[(size_t)f * 2049 + 1024];
            sr += e.x; si += e.y;
            float nr = sr * Tr - si * Ti;
            si = sr * Ti + si * Tr; sr = nr;
            Zb[(size_t)f * 2048 + 1024] = make_float2(sr * SCL, -si * SCL);
        }
    }
}

// ---- inverse FFT: 2 frames per block, 512 threads, 32 KB (4 blocks/CU)
__global__ __launch_bounds__(512, 8) void k_fft_inv(float* __restrict__ ws) {
    __shared__ float B[8192];
    int tid = threadIdx.x;
    int be = blockIdx.x >> 3, fg = blockIdx.x & 7;
    const float2* Zbase = (const float2*)(ws + OFF_Z) + (size_t)(be * 16 + fg * 2) * 2048;
#pragma unroll
    for (int it = 0; it < 2; ++it) {
        int idx = tid + it * 512;
        int n0 = idx * 2;
        int p0 = swz(permf(n0)), p1 = swz(permf(n0 + 1));
#pragma unroll
        for (int j2 = 0; j2 < 2; ++j2) {
            float4 v = ((const float4*)(Zbase + (size_t)j2 * 2048))[idx];
            float* cr = B + j2 * 4096;
            float* ci = cr + 2048;
            cr[p0] = v.x; ci[p0] = v.y;
            cr[p1] = v.z; ci[p1] = v.w;
        }
    }
    __syncthreads();
    STAGE2X(r4i_core, i_ * 4, 1, 0.0f);
    STAGE2X(r4i_core, (i_ & 127) * 16 + (i_ >> 7), 4, (float)(i_ >> 7) * (TWO_PI / 16.0f));
    STAGE2X(r4i_core, (i_ & 31) * 64 + (i_ >> 5), 16, (float)(i_ >> 5) * (TWO_PI / 64.0f));
    STAGE2X(r4i_core, (i_ >> 6) * 256 + (i_ & 63), 64, (float)(i_ & 63) * (TWO_PI / 256.0f));
    STAGE2X(r4i_core, (i_ >> 8) * 1024 + (i_ & 255), 256, (float)(i_ & 255) * (TWO_PI / 1024.0f));
    // radix-2 DIT, h=1024 (sincos shared across buffers)
#pragma unroll
    for (int it = 0; it < 2; ++it) {
        int i = tid + it * 512;
        int sj = swz(i), sjb = swz(i + 1024);
        float s, c; __sincosf((float)i * (TWO_PI / 2048.0f), &s, &c);
#pragma unroll
        for (int j2 = 0; j2 < 2; ++j2) {
            float* cr = B + j2 * 4096;
            float* ci = cr + 2048;
            float br = cr[sjb], bi = ci[sjb];
            float tr = br * c - bi * s, ti2 = br * s + bi * c;
            float ar = cr[sj], ai = ci[sj];
            cr[sj] = ar + tr;  ci[sj] = ai + ti2;
            cr[sjb] = ar - tr; ci[sjb] = ai - ti2;
        }
    }
    __syncthreads();
    float2* Fbase = (float2*)(ws + OFF_ET) + (size_t)(be * 16 + fg * 2) * 2048;
#pragma unroll
    for (int j2 = 0; j2 < 2; ++j2) {
        float* cr = B + j2 * 4096;
        float* ci = cr + 2048;
        float2* Fg = Fbase + (size_t)j2 * 2048;
#pragma unroll
        for (int it = 0; it < 4; ++it) {
            int m = tid + it * 512;
            Fg[m] = make_float2(cr[swz(m)], ci[swz(m)]);
        }
    }
}

// ---- gather + fused overlap-add (b uniform per block -> scalar indices)
__global__ __launch_bounds__(256) void k_segment(const float* __restrict__ ws,
                                                 const int* __restrict__ indices,
                                                 float* __restrict__ out) {
    __shared__ int ste[16];
    int tid = threadIdx.x;
    int b = blockIdx.y;
    if (tid < 16) ste[tid] = indices[b * 16 + tid] * 256;
    __syncthreads();
    int g = blockIdx.x * 256 + tid;
    int t = g << 2;
    const float* F = ws + OFF_ET;
    float4 acc = make_float4(0.f, 0.f, 0.f, 0.f);
#pragma unroll
    for (int e = 0; e < 16; ++e) {
        int te = ste[e];
        if (t >= te) {
            int d = t - te;
            int j = d >> 11, r = d & 2047;
            size_t base = (size_t)(b * 16 + e) * 65536;
            float4 v = *(const float4*)(F + base + j * 4096 + r);
            acc.x += v.x; acc.y += v.y; acc.z += v.z; acc.w += v.w;
            if (j >= 1) {
                float4 w = *(const float4*)(F + base + (j - 1) * 4096 + 2048 + r);
                acc.x += w.x; acc.y += w.y; acc.z += w.z; acc.w += w.w;
            }
        }
    }
    ((float4*)out)[(size_t)b * 8192 + g] = acc;
}

extern "C" void kernel_launch(void* const* d_in, const int* in_sizes, int n_in,
                              void* d_out, int out_size, void* d_ws, size_t ws_size,
                              hipStream_t stream) {
    const float* env = (const float*)d_in[0];
    const float* tf = (const float*)d_in[1];
    const float* noise = (const float*)d_in[2];
    const int* indices = (const int*)d_in[3];
    float* ws = (float*)d_ws;
    float* out = (float*)d_out;

    k_fwd<<<dim3(1024), dim3(512), 0, stream>>>(env, noise, tf, ws);
    k_recur<<<dim3(4, 128), dim3(256), 0, stream>>>(tf, ws);
    k_fft_inv<<<dim3(1024), dim3(512), 0, stream>>>(ws);
    k_segment<<<dim3(32, 8), dim3(256), 0, stream>>>(ws, indices, out);
}

// Round 12
// 76.752 us; speedup vs baseline: 1.2057x; 1.1325x over previous
//
#include <hip/hip_runtime.h>
#include <hip/hip_fp16.h>
#include <math.h>

#define TWO_PI 6.283185307179586f

// workspace layout (float offsets; E/Z/F regions hold halves)
#define OFF_F    0ull          // frames [be][f][4096] __half   = 4194304 floats
#define OFF_E    4194304ull    // E [be][f][2049] __half2       = 4196352 floats
#define OFF_MAXP 8390656ull    // 512 partial maxima (4 per be)
#define OFF_Z    8391680ull    // Z' [be][f][2048] __half2      = 4194304 floats

__device__ __forceinline__ int swz(int n) { return n ^ ((n >> 5) & 31); }

// position of natural index k after DIF with radices [2,4,4,4,4,4]
__device__ __forceinline__ int permf(int k) {
    return ((k & 1) << 10) | (((k >> 1) & 3) << 8) | (((k >> 3) & 3) << 6)
         | (((k >> 5) & 3) << 4) | (((k >> 7) & 3) << 2) | ((k >> 9) & 3);
}

__device__ __forceinline__ void r4f_core(float* cr, float* ci, int p0, int p1, int p2, int p3,
                                         float c1, float s1, float c2, float s2, float c3, float s3) {
    float ar = cr[p0], ai = ci[p0];
    float br = cr[p1], bi = ci[p1];
    float crr = cr[p2], cri = ci[p2];
    float drr = cr[p3], dri = ci[p3];
    float u0r = ar + crr, u0i = ai + cri;
    float u1r = ar - crr, u1i = ai - cri;
    float u2r = br + drr, u2i = bi + dri;
    float u3r = br - drr, u3i = bi - dri;
    cr[p0] = u0r + u2r; ci[p0] = u0i + u2i;
    float z1r = u1r + u3i, z1i = u1i - u3r;            // u1 - i*u3
    cr[p1] = z1r * c1 + z1i * s1; ci[p1] = z1i * c1 - z1r * s1;
    float z2r = u0r - u2r, z2i = u0i - u2i;
    cr[p2] = z2r * c2 + z2i * s2; ci[p2] = z2i * c2 - z2r * s2;
    float z3r = u1r - u3i, z3i = u1i + u3r;            // u1 + i*u3
    cr[p3] = z3r * c3 + z3i * s3; ci[p3] = z3i * c3 - z3r * s3;
}

__device__ __forceinline__ void r4i_core(float* cr, float* ci, int p0, int p1, int p2, int p3,
                                         float c1, float s1, float c2, float s2, float c3, float s3) {
    float z0r = cr[p0], z0i = ci[p0];
    float z1r = cr[p1], z1i = ci[p1];
    float z2r = cr[p2], z2i = ci[p2];
    float z3r = cr[p3], z3i = ci[p3];
    float t1r = z1r * c1 - z1i * s1, t1i = z1i * c1 + z1r * s1;
    float t2r = z2r * c2 - z2i * s2, t2i = z2i * c2 + z2r * s2;
    float t3r = z3r * c3 - z3i * s3, t3i = z3i * c3 + z3r * s3;
    float u0r = z0r + t2r, u0i = z0i + t2i;
    float u1r = z0r - t2r, u1i = z0i - t2i;
    float u2r = t1r + t3r, u2i = t1i + t3i;
    float u3r = t1r - t3r, u3i = t1i - t3i;
    cr[p0] = u0r + u2r; ci[p0] = u0i + u2i;
    cr[p1] = u1r - u3i; ci[p1] = u1i + u3r;            // u1 + i*u3
    cr[p2] = u0r - u2r; ci[p2] = u0i - u2i;
    cr[p3] = u1r + u3i; ci[p3] = u1i - u3r;            // u1 - i*u3
}

// one radix-4 stage over 4 buffers with 1024 threads
#define STAGE4X(CORE, JEXPR, H, ANGEXPR)                                       \
    {                                                                          \
        _Pragma("unroll")                                                      \
        for (int half_ = 0; half_ < 2; ++half_) {                              \
            int b_ = tid + half_ * 1024;                                       \
            int i_ = b_ & 511;                                                 \
            float* cr_ = B + (b_ >> 9) * 4096;                                 \
            float* ci_ = cr_ + 2048;                                           \
            int j_ = (JEXPR);                                                  \
            int p0 = swz(j_), p1 = swz(j_ + (H)), p2 = swz(j_ + 2 * (H)),      \
                p3 = swz(j_ + 3 * (H));                                        \
            float s1, c1; __sincosf((ANGEXPR), &s1, &c1);                      \
            float c2 = c1 * c1 - s1 * s1, s2 = 2.f * c1 * s1;                  \
            float c3 = c1 * c2 - s1 * s2, s3 = s1 * c2 + c1 * s2;              \
            CORE(cr_, ci_, p0, p1, p2, p3, c1, s1, c2, s2, c3, s3);            \
        }                                                                      \
    }                                                                          \
    __syncthreads();

// ---- fused: energy + 4x forward FFT + per-quarter tf max (512 blocks, 2/CU)
__global__ __launch_bounds__(1024, 8) void k_fwd(const float* __restrict__ env,
                                                 const float* __restrict__ noise,
                                                 const float* __restrict__ tf,
                                                 float* __restrict__ ws) {
    __shared__ float B[16384];   // 4 FFTs x (cr[2048], ci[2048]) = 64 KB
    int tid = threadIdx.x;
    int id = blockIdx.x;
    int xcd = id & 7, slot = id >> 3;
    int be = xcd * 16 + (slot >> 2);
    int fg = slot & 3;                       // f = fg*4 .. fg*4+3
    const float4* env4 = (const float4*)env;
    const float4* noi4 = (const float4*)noise;
    size_t base = (size_t)be * 16384 + fg;
#pragma unroll
    for (int it = 0; it < 4; ++it) {
        int n = it * 1024 + tid;
        float4 e = env4[base + (size_t)n * 4];
        float4 z = noi4[base + (size_t)n * 4];
        float v0 = e.x * (z.x * 2.0f - 1.0f);
        float v1 = e.y * (z.y * 2.0f - 1.0f);
        float v2 = e.z * (z.z * 2.0f - 1.0f);
        float v3 = e.w * (z.w * 2.0f - 1.0f);
        int m = swz(n >> 1) + (n & 1) * 2048;   // cr at +0, ci at +2048
        B[m] = v0; B[4096 + m] = v1; B[8192 + m] = v2; B[12288 + m] = v3;
    }
    __syncthreads();
    // radix-2 DIF, h=1024 (twiddle shared across buffers)
    {
        int i = tid;
        int sj = swz(i), sjb = swz(i + 1024);
        float s, c; __sincosf((float)i * (TWO_PI / 2048.0f), &s, &c);
#pragma unroll
        for (int j4 = 0; j4 < 4; ++j4) {
            float* cr = B + j4 * 4096;
            float* ci = cr + 2048;
            float ar = cr[sj], ai = ci[sj], br = cr[sjb], bi = ci[sjb];
            float dr = ar - br, di = ai - bi;
            cr[sj] = ar + br; ci[sj] = ai + bi;
            cr[sjb] = dr * c + di * s; ci[sjb] = di * c - dr * s;
        }
    }
    __syncthreads();
    STAGE4X(r4f_core, (i_ >> 8) * 1024 + (i_ & 255), 256, (float)(i_ & 255) * (TWO_PI / 1024.0f));
    STAGE4X(r4f_core, (i_ >> 6) * 256 + (i_ & 63), 64, (float)(i_ & 63) * (TWO_PI / 256.0f));
    STAGE4X(r4f_core, (i_ & 31) * 64 + (i_ >> 5), 16, (float)(i_ >> 5) * (TWO_PI / 64.0f));
    STAGE4X(r4f_core, (i_ & 127) * 16 + (i_ >> 7), 4, (float)(i_ >> 7) * (TWO_PI / 16.0f));
    STAGE4X(r4f_core, i_ * 4, 1, 0.0f);
    // rfft unpack -> E (half2), indices/twiddles shared across the 4 buffers
    __half2* Ebase = (__half2*)(ws + OFF_E) + (size_t)(be * 16 + fg * 4) * 2049;
    for (int k = tid; k <= 1024; k += 1024) {
        int pk = swz(permf(k));
        int pm = swz(permf((2048 - k) & 2047));
        float s4, c4; __sincosf((float)k * (TWO_PI / 4096.0f), &s4, &c4);
#pragma unroll
        for (int j4 = 0; j4 < 4; ++j4) {
            float* cr = B + j4 * 4096;
            float* ci = cr + 2048;
            float zkr = cr[pk], zki = ci[pk], zmr = cr[pm], zmi = ci[pm];
            float xer = 0.5f * (zkr + zmr), xei = 0.5f * (zki - zmi);
            float xor_ = 0.5f * (zki + zmi), xoi = 0.5f * (zmr - zkr);
            float wr = xor_ * c4 + xoi * s4;
            float wi = xoi * c4 - xor_ * s4;
            __half2* Eg = Ebase + (size_t)j4 * 2049;
            Eg[k] = __floats2half2_rn(xer + wr, xei + wi);
            Eg[2048 - k] = __floats2half2_rn(xer - wr, wi - xei);
        }
    }
    __syncthreads();
    // tf max over this block's bin quarter (reuses B)
    const float4* ab4 = (const float4*)(tf + (size_t)be * 65568);
    int b0 = fg * 513;
    int nb = (fg == 3) ? 510 : 513;          // 3*513 + 510 = 2049 bins
    float mx = 0.f;
    for (int u = tid; u < nb * 4; u += 1024) {
        int g = u >> 2, e = u & 3;
        int bin = b0 + g;
        float4 A = ab4[bin * 8 + e];
        float4 Bv = ab4[bin * 8 + e + 4];
        mx = fmaxf(mx, fmaxf(fmaxf(A.x * A.x + Bv.x * Bv.x, A.y * A.y + Bv.y * Bv.y),
                             fmaxf(A.z * A.z + Bv.z * Bv.z, A.w * A.w + Bv.w * Bv.w)));
    }
    B[tid] = mx;
    __syncthreads();
    for (int s = 512; s > 0; s >>= 1) {
        if (tid < s) B[tid] = fmaxf(B[tid], B[tid + s]);
        __syncthreads();
    }
    if (tid == 0) ws[OFF_MAXP + be * 4 + fg] = B[0];
}

// ---- per-bin recurrence on pair (k, 2048-k) + fused irfft pre-pack -> Z' (half2)
__global__ __launch_bounds__(256) void k_recur(const float* __restrict__ tf,
                                               float* __restrict__ ws) {
    __shared__ float sm2lo[256 * 17], simlo[256 * 17];
    __shared__ float sm2hi[256 * 17], simhi[256 * 17];
    int tid = threadIdx.x;
    int be = blockIdx.y;
    int k0 = blockIdx.x << 8;          // 0,256,512,768
    int hi0 = 1793 - k0;               // hi bins [hi0, hi0+255]
    const float* tfb = tf + (size_t)be * 65568;
    const float4* ab4 = (const float4*)tfb;
    const float4* im4 = (const float4*)(tfb + 32784);

    for (int u = tid; u < 2048; u += 256) {
        int half = u >> 10, v = u & 1023;
        int g = v >> 2, e = v & 3;
        int bin = half ? (hi0 + g) : (k0 + g);
        float4 A = ab4[bin * 8 + e];
        float4 Bv = ab4[bin * 8 + e + 4];
        float4 I = im4[bin * 4 + e];
        int o = g * 17 + e * 4;
        float* sm = half ? sm2hi : sm2lo;
        float* si = half ? simhi : simlo;
        sm[o + 0] = A.x * A.x + Bv.x * Bv.x;
        sm[o + 1] = A.y * A.y + Bv.y * Bv.y;
        sm[o + 2] = A.z * A.z + Bv.z * Bv.z;
        sm[o + 3] = A.w * A.w + Bv.w * Bv.w;
        si[o + 0] = I.x; si[o + 1] = I.y; si[o + 2] = I.z; si[o + 3] = I.w;
    }
    __syncthreads();

    int k = k0 + tid;
    int m = 2048 - k;
    int rhi = 255 - tid;
    const float* mp = ws + OFF_MAXP + be * 4;
    float m2x = fmaxf(fmaxf(mp[0], mp[1]), fmaxf(mp[2], mp[3]));
    float rden = 1.0f / (sqrtf(m2x) + 1e-8f);
    const __half2* Eb = (const __half2*)(ws + OFF_E) + (size_t)be * 16 * 2049;
    __half2* Zb = (__half2*)(ws + OFF_Z) + (size_t)be * 16 * 2048;
    float2 evlo[16], evhi[16];
#pragma unroll
    for (int f = 0; f < 16; ++f) {
        evlo[f] = __half22float2(Eb[(size_t)f * 2049 + k]);
        evhi[f] = __half22float2(Eb[(size_t)f * 2049 + m]);
    }
    float ym = (k == 0) ? 0.0f : 1.0f;
    float s4, c4; __sincosf((float)k * (TWO_PI / 4096.0f), &s4, &c4);
    const float SCL = 1.0f / 2048.0f;
    float srl = 0.f, sil = 0.f, srh = 0.f, sih = 0.f;
#pragma unroll
    for (int f = 0; f < 16; ++f) {
        float mh = sqrtf(sm2lo[tid * 17 + f]) * rden;
        float ph = atan2f(simlo[tid * 17 + f], mh) * 3.14159265358979f;
        float sp, cp; __sincosf(ph, &sp, &cp);
        float Tr = mh * cp, Ti = mh * sp;
        sil *= ym;
        srl += evlo[f].x; sil += evlo[f].y;
        float nr = srl * Tr - sil * Ti;
        sil = srl * Ti + sil * Tr; srl = nr;
        float mh2 = sqrtf(sm2hi[rhi * 17 + f]) * rden;
        float ph2 = atan2f(simhi[rhi * 17 + f], mh2) * 3.14159265358979f;
        float sp2, cp2; __sincosf(ph2, &sp2, &cp2);
        float Tr2 = mh2 * cp2, Ti2 = mh2 * sp2;
        sih *= ym;
        srh += evhi[f].x; sih += evhi[f].y;
        float nr2 = srh * Tr2 - sih * Ti2;
        sih = srh * Ti2 + sih * Tr2; srh = nr2;
        __half2* Zf = Zb + (size_t)f * 2048;
        if (k == 0) {
            float y0 = srl * SCL, yn = srh * SCL;
            Zf[0] = __floats2half2_rn(0.5f * (y0 + yn), 0.5f * (y0 - yn));
        } else {
            float ykr = srl * SCL, yki = sil * SCL;
            float ymr = srh * SCL, ymi = sih * SCL;
            float er = 0.5f * (ykr + ymr), ei = 0.5f * (yki - ymi);
            float dr = ykr - ymr, di = yki + ymi;
            float orr = 0.5f * (dr * c4 - di * s4);
            float oi = 0.5f * (dr * s4 + di * c4);
            Zf[k] = __floats2half2_rn(er - oi, ei + orr);
            Zf[m] = __floats2half2_rn(er + oi, orr - ei);
        }
    }
    if (k0 == 0 && tid == 0) {   // bin 1024 (self-paired)
        float sr = 0.f, si = 0.f;
#pragma unroll
        for (int f = 0; f < 16; ++f) {
            float a = tfb[1024 * 32 + f];
            float b = tfb[1024 * 32 + 16 + f];
            float im = tfb[32784 + 1024 * 16 + f];
            float mh = sqrtf(a * a + b * b) * rden;
            float ph = atan2f(im, mh) * 3.14159265358979f;
            float sp, cp; __sincosf(ph, &sp, &cp);
            float Tr = mh * cp, Ti = mh * sp;
            float2 e = __half22float2(Eb[(size_t)f * 2049 + 1024]);
            sr += e.x; si += e.y;
            float nr = sr * Tr - si * Ti;
            si = sr * Ti + si * Tr; sr = nr;
            Zb[(size_t)f * 2048 + 1024] = __floats2half2_rn(sr * SCL, -si * SCL);
        }
    }
}

// ---- inverse FFT: 4 frames per block, 1024 threads; Z half2 in, F half out
__global__ __launch_bounds__(1024, 8) void k_fft_inv(float* __restrict__ ws) {
    __shared__ float B[16384];
    int tid = threadIdx.x;
    int be = blockIdx.x >> 2, fg = blockIdx.x & 3;
    const __half2* Zbase = (const __half2*)(ws + OFF_Z) + (size_t)(be * 16 + fg * 4) * 2048;
    {
        int n0 = tid * 2;
        int p0 = swz(permf(n0)), p1 = swz(permf(n0 + 1));
#pragma unroll
        for (int j4 = 0; j4 < 4; ++j4) {
            uint2 raw = ((const uint2*)(Zbase + (size_t)j4 * 2048))[tid];
            float2 v0 = __half22float2(*(const __half2*)&raw.x);
            float2 v1 = __half22float2(*(const __half2*)&raw.y);
            float* cr = B + j4 * 4096;
            float* ci = cr + 2048;
            cr[p0] = v0.x; ci[p0] = v0.y;
            cr[p1] = v1.x; ci[p1] = v1.y;
        }
    }
    __syncthreads();
    STAGE4X(r4i_core, i_ * 4, 1, 0.0f);
    STAGE4X(r4i_core, (i_ & 127) * 16 + (i_ >> 7), 4, (float)(i_ >> 7) * (TWO_PI / 16.0f));
    STAGE4X(r4i_core, (i_ & 31) * 64 + (i_ >> 5), 16, (float)(i_ >> 5) * (TWO_PI / 64.0f));
    STAGE4X(r4i_core, (i_ >> 6) * 256 + (i_ & 63), 64, (float)(i_ & 63) * (TWO_PI / 256.0f));
    STAGE4X(r4i_core, (i_ >> 8) * 1024 + (i_ & 255), 256, (float)(i_ & 255) * (TWO_PI / 1024.0f));
    // radix-2 DIT, h=1024 (twiddle shared across buffers)
    {
        int i = tid;
        int sj = swz(i), sjb = swz(i + 1024);
        float s, c; __sincosf((float)i * (TWO_PI / 2048.0f), &s, &c);
#pragma unroll
        for (int j4 = 0; j4 < 4; ++j4) {
            float* cr = B + j4 * 4096;
            float* ci = cr + 2048;
            float br = cr[sjb], bi = ci[sjb];
            float tr = br * c - bi * s, ti2 = br * s + bi * c;
            float ar = cr[sj], ai = ci[sj];
            cr[sj] = ar + tr;  ci[sj] = ai + ti2;
            cr[sjb] = ar - tr; ci[sjb] = ai - ti2;
        }
    }
    __syncthreads();
    __half2* Fbase = (__half2*)(ws + OFF_F) + (size_t)(be * 16 + fg * 4) * 2048;
#pragma unroll
    for (int j4 = 0; j4 < 4; ++j4) {
        float* cr = B + j4 * 4096;
        float* ci = cr + 2048;
        __half2* Fg = Fbase + (size_t)j4 * 2048;
#pragma unroll
        for (int it = 0; it < 2; ++it) {
            int m = tid + it * 1024;
            Fg[m] = __floats2half2_rn(cr[swz(m)], ci[swz(m)]);
        }
    }
}

// ---- gather + fused overlap-add (F half in, f32 out)
__global__ __launch_bounds__(256) void k_segment(const float* __restrict__ ws,
                                                 const int* __restrict__ indices,
                                                 float* __restrict__ out) {
    __shared__ int ste[16];
    int tid = threadIdx.x;
    int b = blockIdx.y;
    if (tid < 16) ste[tid] = indices[b * 16 + tid] * 256;
    __syncthreads();
    int g = blockIdx.x * 256 + tid;
    int t = g << 2;
    const __half* F = (const __half*)(ws + OFF_F);
    float4 acc = make_float4(0.f, 0.f, 0.f, 0.f);
#pragma unroll
    for (int e = 0; e < 16; ++e) {
        int te = ste[e];
        if (t >= te) {
            int d = t - te;
            int j = d >> 11, r = d & 2047;
            size_t base = (size_t)(b * 16 + e) * 65536;
            uint2 raw = *(const uint2*)(F + base + j * 4096 + r);
            float2 a0 = __half22float2(*(const __half2*)&raw.x);
            float2 a1 = __half22float2(*(const __half2*)&raw.y);
            acc.x += a0.x; acc.y += a0.y; acc.z += a1.x; acc.w += a1.y;
            if (j >= 1) {
                uint2 rw2 = *(const uint2*)(F + base + (j - 1) * 4096 + 2048 + r);
                float2 b0 = __half22float2(*(const __half2*)&rw2.x);
                float2 b1 = __half22float2(*(const __half2*)&rw2.y);
                acc.x += b0.x; acc.y += b0.y; acc.z += b1.x; acc.w += b1.y;
            }
        }
    }
    ((float4*)out)[(size_t)b * 8192 + g] = acc;
}

extern "C" void kernel_launch(void* const* d_in, const int* in_sizes, int n_in,
                              void* d_out, int out_size, void* d_ws, size_t ws_size,
                              hipStream_t stream) {
    const float* env = (const float*)d_in[0];
    const float* tf = (const float*)d_in[1];
    const float* noise = (const float*)d_in[2];
    const int* indices = (const int*)d_in[3];
    float* ws = (float*)d_ws;
    float* out = (float*)d_out;

    k_fwd<<<dim3(512), dim3(1024), 0, stream>>>(env, noise, tf, ws);
    k_recur<<<dim3(4, 128), dim3(256), 0, stream>>>(tf, ws);
    k_fft_inv<<<dim3(512), dim3(1024), 0, stream>>>(ws);
    k_segment<<<dim3(32, 8), dim3(256), 0, stream>>>(ws, indices, out);
}